// Round 6
// baseline (458.446 us; speedup 1.0000x reference)
//
#include <hip/hip_runtime.h>
#include <math.h>

// HashGrid: 8 LODs, hashed trilinear interp, 1 feature/entry, summed over LODs.
// LODS  = [17, 27, 44, 71, 116, 191, 313, res7(host-computed, 512 or 513)]
// SIZES = [4913, 19683, 85184, 357911, 2^19, 2^19, 2^19, 2^19]
// codebook layout: [8][524288][1] float32.
//
// R6: line-request reduction on the pow2 tables (LOD4..7) via the PRIME0=1
// x-pair trick: unmodded hash H -> i100 = H^1 when ix even, and for pow2
// masks (H^1)&m == (H&m)^1, so {i000,i100} share one aligned dword.
// Always load the 4 pair-dwords (covers all x0 corners + x1 for even-ix
// lanes); only odd-ix lanes take a masked 4xu16 path. 48 -> 40 avg
// line-requests per point (-17%).

static constexpr unsigned CB_STRIDE = 524288u;
static constexpr int S0 = 4913;    // 17^3
static constexpr int S1 = 19683;   // 27^3
// ws (bf16) element offsets for LOD2..7
static constexpr int WO2 = 0;        // 85184
static constexpr int WO3 = 85184;    // 357911
static constexpr int WO4 = 443104;   // 524288 (4B-aligned: 443104*2 % 4 == 0)
static constexpr int WO5 = 967392;
static constexpr int WO6 = 1491680;
static constexpr int WO7 = 2015968;
static constexpr size_t WS_NEED_BYTES = 2540256u * 2u;  // 5.08 MB

__device__ __forceinline__ unsigned short f32_to_bf16_rne(float f) {
    unsigned u = __float_as_uint(f);
    u = (u + 0x7FFFu + ((u >> 16) & 1u)) >> 16;
    return (unsigned short)u;
}
__device__ __forceinline__ float bf16_to_f32(unsigned short s) {
    return __uint_as_float(((unsigned)s) << 16);
}

struct I8 { unsigned a0, a1, a2, a3, a4, a5, a6, a7; };
struct R8 { unsigned short v0, v1, v2, v3, v4, v5, v6, v7; };
struct W3 { float x, y, z; };

template <unsigned SIZE, bool POW2>
__device__ __forceinline__ I8 idx8(float p01x, float p01y, float p01z, int res, W3& fr)
{
    const float rm1 = (float)(res - 1);
    float xx = p01x * rm1, yy = p01y * rm1, zz = p01z * rm1;
    const float cmax = (float)(res - 2);
    float fx = fminf(fmaxf(floorf(xx), 0.0f), cmax);
    float fy = fminf(fmaxf(floorf(yy), 0.0f), cmax);
    float fz = fminf(fmaxf(floorf(zz), 0.0f), cmax);
    fr.x = xx - fx; fr.y = yy - fy; fr.z = zz - fz;
    const unsigned ix = (unsigned)(int)fx;
    const unsigned iy = (unsigned)(int)fy;
    const unsigned iz = (unsigned)(int)fz;

    const unsigned hx0 = ix;                  // PRIME0 = 1
    const unsigned hx1 = ix + 1u;
    const unsigned hy0 = iy * 2654435761u;
    const unsigned hy1 = hy0 + 2654435761u;
    const unsigned hz0 = iz * 805459861u;
    const unsigned hz1 = hz0 + 805459861u;

    unsigned v0 = hx0 ^ hy0 ^ hz0;
    unsigned v1 = hx0 ^ hy0 ^ hz1;
    unsigned v2 = hx0 ^ hy1 ^ hz0;
    unsigned v3 = hx0 ^ hy1 ^ hz1;
    unsigned v4 = hx1 ^ hy0 ^ hz0;
    unsigned v5 = hx1 ^ hy0 ^ hz1;
    unsigned v6 = hx1 ^ hy1 ^ hz0;
    unsigned v7 = hx1 ^ hy1 ^ hz1;

    if (POW2) {
        const unsigned m = SIZE - 1u;
        v0 &= m; v1 &= m; v2 &= m; v3 &= m; v4 &= m; v5 &= m; v6 &= m; v7 &= m;
    } else {
        v0 %= SIZE; v1 %= SIZE; v2 %= SIZE; v3 %= SIZE;
        v4 %= SIZE; v5 %= SIZE; v6 %= SIZE; v7 %= SIZE;
    }
    I8 o; o.a0 = v0; o.a1 = v1; o.a2 = v2; o.a3 = v3;
          o.a4 = v4; o.a5 = v5; o.a6 = v6; o.a7 = v7;
    return o;
}

__device__ __forceinline__ R8 gather8(const unsigned short* __restrict__ t, I8 o)
{
    R8 r;
    r.v0 = t[o.a0]; r.v1 = t[o.a1]; r.v2 = t[o.a2]; r.v3 = t[o.a3];
    r.v4 = t[o.a4]; r.v5 = t[o.a5]; r.v6 = t[o.a6]; r.v7 = t[o.a7];
    return r;
}

__device__ __forceinline__ float acc8(R8 r, W3 f)
{
    const float wx1 = f.x, wx0 = 1.0f - f.x;
    const float wy1 = f.y, wy0 = 1.0f - f.y;
    const float wz1 = f.z, wz0 = 1.0f - f.z;
    const float w00 = wy0 * wz0, w01 = wy0 * wz1;
    const float w10 = wy1 * wz0, w11 = wy1 * wz1;
    const float sx0 = bf16_to_f32(r.v0) * w00 + bf16_to_f32(r.v1) * w01
                    + bf16_to_f32(r.v2) * w10 + bf16_to_f32(r.v3) * w11;
    const float sx1 = bf16_to_f32(r.v4) * w00 + bf16_to_f32(r.v5) * w01
                    + bf16_to_f32(r.v6) * w10 + bf16_to_f32(r.v7) * w11;
    return wx0 * sx0 + wx1 * sx1;
}

// pair-dword unpack: pair covers table entries {I&~1, I|1}; sel = I&1.
// v0 = entry I (always valid). v1 = entry I^1 if even ix, else the u16 load.
__device__ __forceinline__ void unpack2(unsigned pair, unsigned sel, bool oddx,
                                        unsigned short oval, float& v0, float& v1)
{
    const unsigned short lo = (unsigned short)(pair & 0xffffu);
    const unsigned short hi = (unsigned short)(pair >> 16);
    const unsigned short e0 = sel ? hi : lo;
    const unsigned short eo = sel ? lo : hi;
    v0 = bf16_to_f32(e0);
    v1 = bf16_to_f32(oddx ? oval : eo);
}

// pow2 LOD with x-pair dword merge; self-contained (issue + consume).
__device__ __forceinline__ float lod_pow2_merged(float p01x, float p01y, float p01z,
                                                 int res,
                                                 const unsigned short* __restrict__ t)
{
    const float rm1 = (float)(res - 1);
    float xx = p01x * rm1, yy = p01y * rm1, zz = p01z * rm1;
    const float cmax = (float)(res - 2);
    float fx = fminf(fmaxf(floorf(xx), 0.0f), cmax);
    float fy = fminf(fmaxf(floorf(yy), 0.0f), cmax);
    float fz = fminf(fmaxf(floorf(zz), 0.0f), cmax);
    const float frx = xx - fx, fry = yy - fy, frz = zz - fz;
    const unsigned ix = (unsigned)(int)fx;
    const unsigned iy = (unsigned)(int)fy;
    const unsigned iz = (unsigned)(int)fz;

    const unsigned hy0 = iy * 2654435761u, hy1 = hy0 + 2654435761u;
    const unsigned hz0 = iz * 805459861u,  hz1 = hz0 + 805459861u;
    const unsigned m = 524287u;

    const unsigned I00 = (ix ^ hy0 ^ hz0) & m;
    const unsigned I01 = (ix ^ hy0 ^ hz1) & m;
    const unsigned I10 = (ix ^ hy1 ^ hz0) & m;
    const unsigned I11 = (ix ^ hy1 ^ hz1) & m;

    // 4 aligned dword loads: each covers {I&~1, I|1} = {I, I^1}
    const unsigned p00 = *reinterpret_cast<const unsigned*>(t + (I00 & ~1u));
    const unsigned p01 = *reinterpret_cast<const unsigned*>(t + (I01 & ~1u));
    const unsigned p10 = *reinterpret_cast<const unsigned*>(t + (I10 & ~1u));
    const unsigned p11 = *reinterpret_cast<const unsigned*>(t + (I11 & ~1u));

    // odd-ix lanes need true x1 corners: ((ix+1)^hy^hz)&m
    const unsigned hx1 = ix + 1u;
    const unsigned J00 = (hx1 ^ hy0 ^ hz0) & m;
    const unsigned J01 = (hx1 ^ hy0 ^ hz1) & m;
    const unsigned J10 = (hx1 ^ hy1 ^ hz0) & m;
    const unsigned J11 = (hx1 ^ hy1 ^ hz1) & m;
    unsigned short o00 = 0, o01 = 0, o10 = 0, o11 = 0;
    const bool oddx = (ix & 1u) != 0u;
    if (oddx) { o00 = t[J00]; o01 = t[J01]; o10 = t[J10]; o11 = t[J11]; }

    float v000, v100, v001, v101, v010, v110, v011, v111;
    unpack2(p00, I00 & 1u, oddx, o00, v000, v100);
    unpack2(p01, I01 & 1u, oddx, o01, v001, v101);
    unpack2(p10, I10 & 1u, oddx, o10, v010, v110);
    unpack2(p11, I11 & 1u, oddx, o11, v011, v111);

    const float wx1 = frx, wx0 = 1.0f - frx;
    const float wy1 = fry, wy0 = 1.0f - fry;
    const float wz1 = frz, wz0 = 1.0f - frz;
    const float w00 = wy0 * wz0, w01 = wy0 * wz1;
    const float w10 = wy1 * wz0, w11 = wy1 * wz1;
    const float sx0 = v000 * w00 + v001 * w01 + v010 * w10 + v011 * w11;
    const float sx1 = v100 * w00 + v101 * w01 + v110 * w10 + v111 * w11;
    return wx0 * sx0 + wx1 * sx1;
}

// prep: convert LOD2..7 table prefixes to bf16 in ws
__global__ __launch_bounds__(1024)
void HashGrid_convert_kernel(const float* __restrict__ codebook,
                             unsigned short* __restrict__ ws)
{
    const int lod = blockIdx.y;  // 0..5 -> LOD2..7
    const int sizes[6] = {85184, 357911, 524288, 524288, 524288, 524288};
    const int offs[6]  = {WO2, WO3, WO4, WO5, WO6, WO7};
    const int idx = blockIdx.x * 1024 + threadIdx.x;
    if (idx < sizes[lod])
        ws[offs[lod] + idx] = f32_to_bf16_rne(codebook[(unsigned)(lod + 2) * CB_STRIDE + idx]);
}

__global__ __launch_bounds__(1024, 8)
void HashGrid_88278757802387_kernel(const float* __restrict__ pts,
                                    const float* __restrict__ codebook,
                                    const unsigned short* __restrict__ ws,
                                    float* __restrict__ out,
                                    int n, int res7)
{
    __shared__ unsigned short sm[S0 + S1];  // 49.2 KB -> 2 blocks/CU
    for (int j = threadIdx.x; j < S0 + S1; j += 1024)
        sm[j] = f32_to_bf16_rne(j < S0 ? codebook[j] : codebook[CB_STRIDE + (j - S0)]);
    __syncthreads();

    const int i = blockIdx.x * 1024 + threadIdx.x;
    if (i >= n) return;

    const float p01x = pts[3 * i + 0] * 0.5f + 0.5f;
    const float p01y = pts[3 * i + 1] * 0.5f + 0.5f;
    const float p01z = pts[3 * i + 2] * 0.5f + 0.5f;

    // mod tables (unmergeable): issue 16 u16 gathers up front
    W3 fA, fB, fL0, fL1;
    I8 oA = idx8<85184u,  false>(p01x, p01y, p01z, 44, fA);
    I8 oB = idx8<357911u, false>(p01x, p01y, p01z, 71, fB);
    R8 rA = gather8(ws + WO2, oA);
    R8 rB = gather8(ws + WO3, oB);

    // pow2 tables: merged x-pair loads (avg 6 requests each vs 8)
    float acc = lod_pow2_merged(p01x, p01y, p01z, 116,  ws + WO4);
    acc      += lod_pow2_merged(p01x, p01y, p01z, 191,  ws + WO5);
    acc      += lod_pow2_merged(p01x, p01y, p01z, 313,  ws + WO6);
    acc      += lod_pow2_merged(p01x, p01y, p01z, res7, ws + WO7);

    // LDS LODs
    I8 oL0 = idx8<4913u,  false>(p01x, p01y, p01z, 17, fL0);
    I8 oL1 = idx8<19683u, false>(p01x, p01y, p01z, 27, fL1);
    R8 rL0 = gather8(sm, oL0);
    R8 rL1 = gather8(sm + S0, oL1);
    acc += acc8(rL0, fL0) + acc8(rL1, fL1);

    // consume the mod-table batches
    acc += acc8(rA, fA) + acc8(rB, fB);

    out[i] = acc;
}

// fallback (no ws): per-LOD f32 path
__global__ __launch_bounds__(1024, 4)
void HashGrid_fallback_kernel(const float* __restrict__ pts,
                              const float* __restrict__ codebook,
                              float* __restrict__ out,
                              int n, int res7)
{
    const int i = blockIdx.x * 1024 + threadIdx.x;
    if (i >= n) return;
    const float p01x = pts[3 * i + 0] * 0.5f + 0.5f;
    const float p01y = pts[3 * i + 1] * 0.5f + 0.5f;
    const float p01z = pts[3 * i + 2] * 0.5f + 0.5f;
    float acc = 0.0f;
    const int      reslist[8]  = {17, 27, 44, 71, 116, 191, 313, res7};
    const unsigned sizelist[8] = {4913u, 19683u, 85184u, 357911u, 524288u, 524288u, 524288u, 524288u};
    for (int l = 0; l < 8; ++l) {
        const int res = reslist[l];
        const unsigned size = sizelist[l];
        const float rm1 = (float)(res - 1);
        float xx = p01x * rm1, yy = p01y * rm1, zz = p01z * rm1;
        float fx = fminf(fmaxf(floorf(xx), 0.0f), (float)(res - 2));
        float fy = fminf(fmaxf(floorf(yy), 0.0f), (float)(res - 2));
        float fz = fminf(fmaxf(floorf(zz), 0.0f), (float)(res - 2));
        const float frx = xx - fx, fry = yy - fy, frz = zz - fz;
        const unsigned ix = (unsigned)(int)fx, iy = (unsigned)(int)fy, iz = (unsigned)(int)fz;
        const unsigned hy0 = iy * 2654435761u, hy1 = hy0 + 2654435761u;
        const unsigned hz0 = iz * 805459861u,  hz1 = hz0 + 805459861u;
        const unsigned o0 = (ix ^ hy0 ^ hz0) % size,      o1 = (ix ^ hy0 ^ hz1) % size;
        const unsigned o2 = (ix ^ hy1 ^ hz0) % size,      o3 = (ix ^ hy1 ^ hz1) % size;
        const unsigned o4 = ((ix+1u) ^ hy0 ^ hz0) % size, o5 = ((ix+1u) ^ hy0 ^ hz1) % size;
        const unsigned o6 = ((ix+1u) ^ hy1 ^ hz0) % size, o7 = ((ix+1u) ^ hy1 ^ hz1) % size;
        const float* tab = codebook + (unsigned)l * CB_STRIDE;
        const float wx1 = frx, wx0 = 1.0f - frx;
        const float wy1 = fry, wy0 = 1.0f - fry;
        const float wz1 = frz, wz0 = 1.0f - frz;
        const float w00 = wy0*wz0, w01 = wy0*wz1, w10 = wy1*wz0, w11 = wy1*wz1;
        acc += wx0 * (tab[o0]*w00 + tab[o1]*w01 + tab[o2]*w10 + tab[o3]*w11)
             + wx1 * (tab[o4]*w00 + tab[o5]*w01 + tab[o6]*w10 + tab[o7]*w11);
    }
    out[i] = acc;
}

extern "C" void kernel_launch(void* const* d_in, const int* in_sizes, int n_in,
                              void* d_out, int out_size, void* d_ws, size_t ws_size,
                              hipStream_t stream)
{
    const float* pts      = (const float*)d_in[0];
    const float* codebook = (const float*)d_in[1];
    float* out            = (float*)d_out;
    const int n = in_sizes[0] / 3;

    // numpy-matching LOD7 resolution (16*b^7 sits ~1e-12 from 512.0)
    const double b = exp((log(512.0) - log(16.0)) / 7.0);
    const int res7 = (int)(1.0 + floor(16.0 * pow(b, 7.0)));

    const bool use_ws = (d_ws != nullptr) && (ws_size >= WS_NEED_BYTES);
    const int blocks = (n + 1023) / 1024;

    if (use_ws) {
        unsigned short* ws = (unsigned short*)d_ws;
        hipLaunchKernelGGL(HashGrid_convert_kernel, dim3(512, 6), dim3(1024),
                           0, stream, codebook, ws);
        hipLaunchKernelGGL(HashGrid_88278757802387_kernel, dim3(blocks), dim3(1024),
                           0, stream, pts, codebook, ws, out, n, res7);
    } else {
        hipLaunchKernelGGL(HashGrid_fallback_kernel, dim3(blocks), dim3(1024),
                           0, stream, pts, codebook, out, n, res7);
    }
}

// Round 7
// 430.795 us; speedup vs baseline: 1.0642x; 1.0642x over previous
//
#include <hip/hip_runtime.h>
#include <math.h>

// HashGrid: 8 LODs, hashed trilinear interp, 1 feature/entry, summed over LODs.
// LODS  = [17, 27, 44, 71, 116, 191, 313, res7(host-computed, 512 or 513)]
// SIZES = [4913, 19683, 85184, 357911, 2^19, 2^19, 2^19, 2^19]
// codebook layout: [8][524288][1] float32.
//
// R7: drop LDS staging entirely (LOD0 bf16 = 9.8 KB is L1-resident; LOD1
// 39 KB ~L1/L2; staging cost + 1024-block occupancy cap were net losses).
// All 8 LODs gather from a packed bf16 ws image. 256-thread blocks, no LDS
// -> up to 32 waves/CU, no staging traffic, no barrier.

static constexpr unsigned CB_STRIDE = 524288u;
// packed bf16 ws element offsets (all 4B-aligned)
static constexpr int WO0 = 0;        // 4913
static constexpr int WO1 = 4928;     // 19683
static constexpr int WO2 = 24640;    // 85184
static constexpr int WO3 = 109824;   // 357911
static constexpr int WO4 = 467744;   // 524288
static constexpr int WO5 = 992032;   // 524288
static constexpr int WO6 = 1516320;  // 524288
static constexpr int WO7 = 2040608;  // 524288 -> end 2564896
static constexpr size_t WS_NEED_BYTES = 2564896u * 2u;  // 5.13 MB

__device__ __forceinline__ unsigned short f32_to_bf16_rne(float f) {
    unsigned u = __float_as_uint(f);
    u = (u + 0x7FFFu + ((u >> 16) & 1u)) >> 16;
    return (unsigned short)u;
}
__device__ __forceinline__ float bf16_to_f32(unsigned short s) {
    return __uint_as_float(((unsigned)s) << 16);
}

template <unsigned SIZE, bool POW2>
__device__ __forceinline__ float lod_interp(float p01x, float p01y, float p01z,
                                            const unsigned short* __restrict__ t,
                                            int res)
{
    const float rm1 = (float)(res - 1);
    float xx = p01x * rm1, yy = p01y * rm1, zz = p01z * rm1;
    const float cmax = (float)(res - 2);
    float fx = fminf(fmaxf(floorf(xx), 0.0f), cmax);
    float fy = fminf(fmaxf(floorf(yy), 0.0f), cmax);
    float fz = fminf(fmaxf(floorf(zz), 0.0f), cmax);
    const float frx = xx - fx, fry = yy - fy, frz = zz - fz;
    const unsigned ix = (unsigned)(int)fx;
    const unsigned iy = (unsigned)(int)fy;
    const unsigned iz = (unsigned)(int)fz;

    const unsigned hx0 = ix;                  // PRIME0 = 1
    const unsigned hx1 = ix + 1u;
    const unsigned hy0 = iy * 2654435761u;
    const unsigned hy1 = hy0 + 2654435761u;
    const unsigned hz0 = iz * 805459861u;
    const unsigned hz1 = hz0 + 805459861u;

    unsigned v0 = hx0 ^ hy0 ^ hz0;
    unsigned v1 = hx0 ^ hy0 ^ hz1;
    unsigned v2 = hx0 ^ hy1 ^ hz0;
    unsigned v3 = hx0 ^ hy1 ^ hz1;
    unsigned v4 = hx1 ^ hy0 ^ hz0;
    unsigned v5 = hx1 ^ hy0 ^ hz1;
    unsigned v6 = hx1 ^ hy1 ^ hz0;
    unsigned v7 = hx1 ^ hy1 ^ hz1;

    if (POW2) {
        const unsigned m = SIZE - 1u;
        v0 &= m; v1 &= m; v2 &= m; v3 &= m; v4 &= m; v5 &= m; v6 &= m; v7 &= m;
    } else {
        v0 %= SIZE; v1 %= SIZE; v2 %= SIZE; v3 %= SIZE;
        v4 %= SIZE; v5 %= SIZE; v6 %= SIZE; v7 %= SIZE;
    }

    const float t000 = bf16_to_f32(t[v0]);
    const float t001 = bf16_to_f32(t[v1]);
    const float t010 = bf16_to_f32(t[v2]);
    const float t011 = bf16_to_f32(t[v3]);
    const float t100 = bf16_to_f32(t[v4]);
    const float t101 = bf16_to_f32(t[v5]);
    const float t110 = bf16_to_f32(t[v6]);
    const float t111 = bf16_to_f32(t[v7]);

    const float wx1 = frx, wx0 = 1.0f - frx;
    const float wy1 = fry, wy0 = 1.0f - fry;
    const float wz1 = frz, wz0 = 1.0f - frz;
    const float w00 = wy0 * wz0, w01 = wy0 * wz1;
    const float w10 = wy1 * wz0, w11 = wy1 * wz1;
    const float sx0 = t000 * w00 + t001 * w01 + t010 * w10 + t011 * w11;
    const float sx1 = t100 * w00 + t101 * w01 + t110 * w10 + t111 * w11;
    return wx0 * sx0 + wx1 * sx1;
}

// prep: convert all 8 LOD table prefixes to packed bf16 in ws
__global__ __launch_bounds__(1024)
void HashGrid_convert_kernel(const float* __restrict__ codebook,
                             unsigned short* __restrict__ ws)
{
    const int lod = blockIdx.y;  // 0..7
    const int sizes[8] = {4913, 19683, 85184, 357911, 524288, 524288, 524288, 524288};
    const int offs[8]  = {WO0, WO1, WO2, WO3, WO4, WO5, WO6, WO7};
    const int idx = blockIdx.x * 1024 + threadIdx.x;
    if (idx < sizes[lod])
        ws[offs[lod] + idx] = f32_to_bf16_rne(codebook[(unsigned)lod * CB_STRIDE + idx]);
}

__global__ __launch_bounds__(256, 4)
void HashGrid_88278757802387_kernel(const float* __restrict__ pts,
                                    const unsigned short* __restrict__ ws,
                                    float* __restrict__ out,
                                    int n, int res7)
{
    const int i = blockIdx.x * 256 + threadIdx.x;
    if (i >= n) return;

    const float p01x = pts[3 * i + 0] * 0.5f + 0.5f;
    const float p01y = pts[3 * i + 1] * 0.5f + 0.5f;
    const float p01z = pts[3 * i + 2] * 0.5f + 0.5f;

    float acc = 0.0f;
    acc += lod_interp<4913u,   false>(p01x, p01y, p01z, ws + WO0, 17);
    acc += lod_interp<19683u,  false>(p01x, p01y, p01z, ws + WO1, 27);
    acc += lod_interp<85184u,  false>(p01x, p01y, p01z, ws + WO2, 44);
    acc += lod_interp<357911u, false>(p01x, p01y, p01z, ws + WO3, 71);
    acc += lod_interp<524288u, true >(p01x, p01y, p01z, ws + WO4, 116);
    acc += lod_interp<524288u, true >(p01x, p01y, p01z, ws + WO5, 191);
    acc += lod_interp<524288u, true >(p01x, p01y, p01z, ws + WO6, 313);
    acc += lod_interp<524288u, true >(p01x, p01y, p01z, ws + WO7, res7);

    out[i] = acc;
}

// fallback (no ws): per-LOD f32 path straight from codebook
__global__ __launch_bounds__(256, 4)
void HashGrid_fallback_kernel(const float* __restrict__ pts,
                              const float* __restrict__ codebook,
                              float* __restrict__ out,
                              int n, int res7)
{
    const int i = blockIdx.x * 256 + threadIdx.x;
    if (i >= n) return;
    const float p01x = pts[3 * i + 0] * 0.5f + 0.5f;
    const float p01y = pts[3 * i + 1] * 0.5f + 0.5f;
    const float p01z = pts[3 * i + 2] * 0.5f + 0.5f;
    float acc = 0.0f;
    const int      reslist[8]  = {17, 27, 44, 71, 116, 191, 313, res7};
    const unsigned sizelist[8] = {4913u, 19683u, 85184u, 357911u, 524288u, 524288u, 524288u, 524288u};
    for (int l = 0; l < 8; ++l) {
        const int res = reslist[l];
        const unsigned size = sizelist[l];
        const float rm1 = (float)(res - 1);
        float xx = p01x * rm1, yy = p01y * rm1, zz = p01z * rm1;
        float fx = fminf(fmaxf(floorf(xx), 0.0f), (float)(res - 2));
        float fy = fminf(fmaxf(floorf(yy), 0.0f), (float)(res - 2));
        float fz = fminf(fmaxf(floorf(zz), 0.0f), (float)(res - 2));
        const float frx = xx - fx, fry = yy - fy, frz = zz - fz;
        const unsigned ix = (unsigned)(int)fx, iy = (unsigned)(int)fy, iz = (unsigned)(int)fz;
        const unsigned hy0 = iy * 2654435761u, hy1 = hy0 + 2654435761u;
        const unsigned hz0 = iz * 805459861u,  hz1 = hz0 + 805459861u;
        const unsigned o0 = (ix ^ hy0 ^ hz0) % size,      o1 = (ix ^ hy0 ^ hz1) % size;
        const unsigned o2 = (ix ^ hy1 ^ hz0) % size,      o3 = (ix ^ hy1 ^ hz1) % size;
        const unsigned o4 = ((ix+1u) ^ hy0 ^ hz0) % size, o5 = ((ix+1u) ^ hy0 ^ hz1) % size;
        const unsigned o6 = ((ix+1u) ^ hy1 ^ hz0) % size, o7 = ((ix+1u) ^ hy1 ^ hz1) % size;
        const float* tab = codebook + (unsigned)l * CB_STRIDE;
        const float wx1 = frx, wx0 = 1.0f - frx;
        const float wy1 = fry, wy0 = 1.0f - fry;
        const float wz1 = frz, wz0 = 1.0f - frz;
        const float w00 = wy0*wz0, w01 = wy0*wz1, w10 = wy1*wz0, w11 = wy1*wz1;
        acc += wx0 * (tab[o0]*w00 + tab[o1]*w01 + tab[o2]*w10 + tab[o3]*w11)
             + wx1 * (tab[o4]*w00 + tab[o5]*w01 + tab[o6]*w10 + tab[o7]*w11);
    }
    out[i] = acc;
}

extern "C" void kernel_launch(void* const* d_in, const int* in_sizes, int n_in,
                              void* d_out, int out_size, void* d_ws, size_t ws_size,
                              hipStream_t stream)
{
    const float* pts      = (const float*)d_in[0];
    const float* codebook = (const float*)d_in[1];
    float* out            = (float*)d_out;
    const int n = in_sizes[0] / 3;

    // numpy-matching LOD7 resolution (16*b^7 sits ~1e-12 from 512.0)
    const double b = exp((log(512.0) - log(16.0)) / 7.0);
    const int res7 = (int)(1.0 + floor(16.0 * pow(b, 7.0)));

    const bool use_ws = (d_ws != nullptr) && (ws_size >= WS_NEED_BYTES);
    const int blocks = (n + 255) / 256;

    if (use_ws) {
        unsigned short* ws = (unsigned short*)d_ws;
        hipLaunchKernelGGL(HashGrid_convert_kernel, dim3(512, 8), dim3(1024),
                           0, stream, codebook, ws);
        hipLaunchKernelGGL(HashGrid_88278757802387_kernel, dim3(blocks), dim3(256),
                           0, stream, pts, ws, out, n, res7);
    } else {
        hipLaunchKernelGGL(HashGrid_fallback_kernel, dim3(blocks), dim3(256),
                           0, stream, pts, codebook, out, n, res7);
    }
}